// Round 10
// baseline (148.621 us; speedup 1.0000x reference)
//
#include <hip/hip_runtime.h>

typedef short s16x8 __attribute__((ext_vector_type(8)));
typedef float f32x16 __attribute__((ext_vector_type(16)));

// MFMA forced into VGPRs ("v" forbids AGPR; "=&v" keeps dst disjoint).
__device__ __forceinline__ f32x16 mfma0(s16x8 a, s16x8 b) {
    f32x16 d;
    asm volatile("v_mfma_f32_32x32x16_bf16 %0, %1, %2, 0"
                 : "=&v"(d) : "v"(a), "v"(b));
    return d;
}

#define VMIN3(d, a, b, c) \
    asm("v_min3_f32 %0, %1, %2, %3" : "=v"(d) : "v"(a), "v"(b), "v"(c))

#define FOLD16(mn, A) { \
        float u0, u1, u2, u3, u4, v0, v1; \
        VMIN3(u0, A[0],  A[1],  A[2]); \
        VMIN3(u1, A[3],  A[4],  A[5]); \
        VMIN3(u2, A[6],  A[7],  A[8]); \
        VMIN3(u3, A[9],  A[10], A[11]); \
        VMIN3(u4, A[12], A[13], A[14]); \
        VMIN3(v0, u0, u1, u2); \
        VMIN3(v1, u3, u4, A[15]); \
        VMIN3(mn, v0, v1, mn); \
    }

// bf16 round-to-nearest-even helpers
__device__ __forceinline__ unsigned short rne(float f) {
    unsigned u = __float_as_uint(f);
    return (unsigned short)((u + 0x7fffu + ((u >> 16) & 1u)) >> 16);
}
__device__ __forceinline__ float b2f(unsigned short b) {
    return __uint_as_float(((unsigned)b) << 16);
}

// 16-slot hi/lo-split encoding (validated rounds 4-9, absmax 0)
__device__ __forceinline__ void encDf(float x, float y, float z, s16x8& lo, s16x8& hi) {
    const unsigned short hx = rne(x), hy = rne(y), hz = rne(z);
    const float fx = b2f(hx), fy = b2f(hy), fz = b2f(hz);
    const unsigned short lx = rne(x - fx), ly = rne(y - fy), lz = rne(z - fz);
    const float n = fmaf(x, x, fmaf(y, y, z * z));
    const unsigned short nh = rne(n), nl = rne(n - b2f(nh));
    const unsigned short m2hx = rne(-2.f * fx), m2hy = rne(-2.f * fy), m2hz = rne(-2.f * fz);
    const unsigned short m2lx = rne(-2.f * b2f(lx)), m2ly = rne(-2.f * b2f(ly)), m2lz = rne(-2.f * b2f(lz));
    lo[0]=(short)m2hx; lo[1]=(short)m2hy; lo[2]=(short)m2hz; lo[3]=(short)m2hx;
    lo[4]=(short)m2hy; lo[5]=(short)m2hz; lo[6]=(short)m2lx; lo[7]=(short)m2ly;
    hi[0]=(short)m2lz; hi[1]=(short)0x3f80; hi[2]=(short)0x3f80; hi[3]=(short)nh;
    hi[4]=(short)nl;   hi[5]=(short)m2lx;  hi[6]=(short)m2ly;   hi[7]=(short)m2lz;
}

__device__ __forceinline__ void encQf(float x, float y, float z, s16x8& lo, s16x8& hi) {
    const unsigned short hx = rne(x), hy = rne(y), hz = rne(z);
    const float fx = b2f(hx), fy = b2f(hy), fz = b2f(hz);
    const unsigned short lx = rne(x - fx), ly = rne(y - fy), lz = rne(z - fz);
    const float n = fmaf(x, x, fmaf(y, y, z * z));
    const unsigned short nh = rne(n), nl = rne(n - b2f(nh));
    lo[0]=(short)hx; lo[1]=(short)hy; lo[2]=(short)hz; lo[3]=(short)lx;
    lo[4]=(short)ly; lo[5]=(short)lz; lo[6]=(short)hx; lo[7]=(short)hy;
    hi[0]=(short)hz; hi[1]=(short)nh; hi[2]=(short)nl; hi[3]=(short)0x3f80;
    hi[4]=(short)0x3f80; hi[5]=(short)lx; hi[6]=(short)ly; hi[7]=(short)lz;
}

// ---------------------------------------------------------------------------
__global__ void __launch_bounds__(256) preproc(
    const float* __restrict__ pred, const float* __restrict__ tgt,
    char* __restrict__ encQp, char* __restrict__ encQt,
    char* __restrict__ encDp, char* __restrict__ encDt,
    unsigned long long* __restrict__ acc, unsigned* __restrict__ ticket)
{
    const int pid = blockIdx.x * 256 + threadIdx.x;     // [0, 65536)
    if (pid == 0) { *acc = 0ull; *ticket = 0u; }
    const int which = pid >> 15, p = pid & 32767;
    const float* __restrict__ src = which ? tgt : pred;
    char* __restrict__ eQ = which ? encQt : encQp;
    char* __restrict__ eD = which ? encDt : encDp;

    const float x = src[p * 3], y = src[p * 3 + 1], z = src[p * 3 + 2];
    const int b = p >> 13, i = p & 8191;

    s16x8 qlo, qhi, dlo, dhi;
    encQf(x, y, z, qlo, qhi);
    encDf(x, y, z, dlo, dhi);

    {   // db-role: contiguous 16 KiB per 512-point chunk
        const int split = i >> 9, idx = i & 511, tile = idx >> 5, pt = idx & 31;
        char* base = eD + (((size_t)(b * 16 + split)) << 14) + (tile << 10) + (pt << 4);
        *(s16x8*)base = dlo;
        *(s16x8*)(base + 512) = dhi;
    }
    {   // query-role
        const int tile = i >> 5, pt = i & 31;
        char* base = eQ + (((size_t)(b * 256 + tile)) << 10) + (pt << 4);
        *(s16x8*)base = qlo;
        *(s16x8*)(base + 512) = qhi;
    }
}

// ---------------------------------------------------------------------------
// DIAGNOSTIC minpass. VARIANT: 0 = full (R9 kernel, writes part),
// 1 = MFMA+LDS only (folds -> asm sinks), 2 = VALU+LDS only (MFMAs ->
// opaque register touches). REP repeats the main loop idempotently (min of
// identical values) to push the dispatch above the ~40us ws-poison fills so
// rocprof top-5 exposes its counters. V1/V2 write to a dummy region.
// ---------------------------------------------------------------------------
template<int VARIANT, int REP>
__global__ void __launch_bounds__(256) minpass(
    const char* __restrict__ encQp, const char* __restrict__ encQt,
    const char* __restrict__ encDp, const char* __restrict__ encDt,
    float* __restrict__ part, float* __restrict__ dummy)
{
    __shared__ s16x8 sdb[16 * 64];   // 16 KiB

    const int bid = blockIdx.x;
    const int qg = bid & 31, split = (bid >> 5) & 15, b = (bid >> 9) & 3, pass = bid >> 11;
    const char* __restrict__ eQ = pass ? encQt : encQp;
    const char* __restrict__ eD = pass ? encDp : encDt;

    const int tid = threadIdx.x, lane = tid & 63, wid = tid >> 6;

    // stage pre-encoded db chunk: pure linear 16 KiB copy
    {
        const int4* __restrict__ gs = (const int4*)(eD + (((size_t)(b * 16 + split)) << 14));
        int4* ld = (int4*)sdb;
        int4 r0 = gs[tid], r1 = gs[tid + 256], r2 = gs[tid + 512], r3 = gs[tid + 768];
        ld[tid] = r0; ld[tid + 256] = r1; ld[tid + 512] = r2; ld[tid + 768] = r3;
    }

    const int tq = qg * 8 + wid * 2;
    const s16x8* __restrict__ qa = (const s16x8*)(eQ + (((size_t)(b * 256 + tq)) << 10));
    const s16x8 aq0 = qa[lane];
    const s16x8 aq1 = qa[64 + lane];

    f32x16 A0, A1, B0, B1;
    if constexpr (VARIANT == 2) {
#pragma unroll
        for (int i = 0; i < 16; ++i) { A0[i] = 1.f; A1[i] = 2.f; B0[i] = 3.f; B1[i] = 4.f; }
    }

    float mn0 = 3.4e38f, mn1 = 3.4e38f;

    __syncthreads();

    for (int rep = 0; rep < REP; ++rep) {
        s16x8 dA = sdb[lane];
        s16x8 dB = sdb[64 + lane];
        if constexpr (VARIANT != 2) {
            A0 = mfma0(dA, aq0); A1 = mfma0(dA, aq1);
            B0 = mfma0(dB, aq0); B1 = mfma0(dB, aq1);
        } else {
            asm volatile("" : "+v"(A0), "+v"(A1), "+v"(B0), "+v"(B1)
                           : "v"(dA), "v"(dB), "v"(aq0), "v"(aq1));
        }
        dA = sdb[2 * 64 + lane];
        dB = sdb[3 * 64 + lane];
        asm volatile("s_nop 7");

#pragma unroll
        for (int t = 0; t < 16; t += 2) {
            __builtin_amdgcn_sched_barrier(0);
            s16x8 dnA = dA;
            if (t + 4 < 16) dnA = sdb[(t + 4) * 64 + lane];
            if constexpr (VARIANT != 1) { FOLD16(mn0, A0); FOLD16(mn1, A1); }
            else { asm volatile("" :: "v"(A0), "v"(A1)); }
            if (t + 2 < 16) {
                if constexpr (VARIANT != 2) { A0 = mfma0(dA, aq0); A1 = mfma0(dA, aq1); }
                else { asm volatile("" : "+v"(A0), "+v"(A1) : "v"(dA)); }
            }
            dA = dnA;
            __builtin_amdgcn_sched_barrier(0);
            s16x8 dnB = dB;
            if (t + 5 < 16) dnB = sdb[(t + 5) * 64 + lane];
            if constexpr (VARIANT != 1) { FOLD16(mn0, B0); FOLD16(mn1, B1); }
            else { asm volatile("" :: "v"(B0), "v"(B1)); }
            if (t + 3 < 16) {
                if constexpr (VARIANT != 2) { B0 = mfma0(dB, aq0); B1 = mfma0(dB, aq1); }
                else { asm volatile("" : "+v"(B0), "+v"(B1) : "v"(dB)); }
            }
            dB = dnB;
        }
        __builtin_amdgcn_sched_barrier(0);
        asm volatile("" : "+v"(mn0), "+v"(mn1));
    }

    mn0 = fmaxf(fminf(mn0, __shfl_xor(mn0, 32)), 0.0f);
    mn1 = fmaxf(fminf(mn1, __shfl_xor(mn1, 32)), 0.0f);

    if (lane < 32) {
        const size_t qi = ((size_t)pass << 15) + ((size_t)b << 13) + (size_t)tq * 32 + lane;
        float* __restrict__ po = (VARIANT == 0) ? part : dummy;
        po[(size_t)split * 65536 + qi]      = mn0;
        po[(size_t)split * 65536 + qi + 32] = mn1;
    }
}

// ---------------------------------------------------------------------------
#define FIXSCALE 1099511627776.0   // 2^40
#define RBLOCKS 128

__global__ void __launch_bounds__(256) reduce_writeout(
    const float* __restrict__ part, unsigned long long* __restrict__ acc,
    unsigned* __restrict__ ticket, float* __restrict__ out)
{
    const int q0 = blockIdx.x * 512 + threadIdx.x;
    float s = 0.0f;
#pragma unroll
    for (int k = 0; k < 2; ++k) {
        const int qi = q0 + k * 256;
        float v = part[qi];
#pragma unroll
        for (int sp = 1; sp < 16; ++sp) v = fminf(v, part[(size_t)sp * 65536 + qi]);
        s += sqrtf(v);
    }
    for (int off = 32; off; off >>= 1) s += __shfl_down(s, off, 64);
    __shared__ float ws[4];
    if ((threadIdx.x & 63) == 0) ws[threadIdx.x >> 6] = s;
    __syncthreads();
    if (threadIdx.x == 0) {
        const double t = (double)(ws[0] + ws[1] + ws[2] + ws[3]) * (1.0 / 32768.0);
        atomicAdd(acc, (unsigned long long)(t * FIXSCALE));
        __threadfence();
        const unsigned tk = atomicAdd(ticket, 1u);
        if (tk == RBLOCKS - 1) {
            const unsigned long long v = atomicAdd(acc, 0ull);
            out[0] = (float)((double)v * (1.0 / FIXSCALE));
        }
    }
}

// ---------------------------------------------------------------------------
extern "C" void kernel_launch(void* const* d_in, const int* in_sizes, int n_in,
                              void* d_out, int out_size, void* d_ws, size_t ws_size,
                              hipStream_t stream) {
    const float* pred   = (const float*)d_in[0];   // [4,8192,3]
    const float* target = (const float*)d_in[1];   // [4,8192,3]
    float* out = (float*)d_out;

    char* encQp = (char*)d_ws;                       // 1 MiB each
    char* encQt = encQp + (1u << 20);
    char* encDp = encQp + (2u << 20);
    char* encDt = encQp + (3u << 20);
    float* part = (float*)(encQp + (4u << 20));      // [16][65536] = 4 MiB
    unsigned long long* acc = (unsigned long long*)(encQp + (8u << 20));
    unsigned* ticket = (unsigned*)(acc + 1);
    float* dummy = (float*)(encQp + (16u << 20));    // diagnostic sink, 4 MiB

    preproc<<<256, 256, 0, stream>>>(pred, target, encQp, encQt, encDp, encDt, acc, ticket);

    // diagnostics (results discarded into dummy)
    minpass<1, 8><<<4096, 256, 0, stream>>>(encQp, encQt, encDp, encDt, part, dummy);
    minpass<2, 4><<<4096, 256, 0, stream>>>(encQp, encQt, encDp, encDt, part, dummy);

    // the real kernel (REP=2, idempotent)
    minpass<0, 2><<<4096, 256, 0, stream>>>(encQp, encQt, encDp, encDt, part, dummy);

    reduce_writeout<<<RBLOCKS, 256, 0, stream>>>(part, acc, ticket, out);
}

// Round 11
// 34.179 us; speedup vs baseline: 4.3484x; 4.3484x over previous
//
#include <hip/hip_runtime.h>

typedef short s16x8 __attribute__((ext_vector_type(8)));
typedef float f32x16 __attribute__((ext_vector_type(16)));

// MFMA in VGPRs via asm ("v" class forbids AGPR; "=&v" keeps dst disjoint).
// NON-volatile: the scheduler may place it freely; dataflow to the guarded
// fold preserves producer->consumer order.
__device__ __forceinline__ f32x16 mfma0(s16x8 a, s16x8 b) {
    f32x16 d;
    asm("v_mfma_f32_32x32x16_bf16 %0, %1, %2, 0" : "=&v"(d) : "v"(a), "v"(b));
    return d;
}

// Hazard guard: launder the acc tuple through >=24 dead cycles. Every read of
// the acc depends on this asm, so no VALU read can execute sooner than 24 cyc
// after the producing MFMA (16-pass MFMA needs ~18 wait states). The nops are
// wave-private; other resident waves fill the SIMD issue slots.
#define GUARD(A) asm("s_nop 7\n\ts_nop 7\n\ts_nop 7" : "+v"(A))

// 8-op min fold, fminf triples fuse to v_min3 and schedule freely.
__device__ __forceinline__ float fold16(float mn, f32x16 a) {
    const float u0 = fminf(fminf(a[0],  a[1]),  a[2]);
    const float u1 = fminf(fminf(a[3],  a[4]),  a[5]);
    const float u2 = fminf(fminf(a[6],  a[7]),  a[8]);
    const float u3 = fminf(fminf(a[9],  a[10]), a[11]);
    const float u4 = fminf(fminf(a[12], a[13]), a[14]);
    const float v0 = fminf(fminf(u0, u1), u2);
    const float v1 = fminf(fminf(u3, u4), a[15]);
    return fminf(fminf(v0, v1), mn);
}

// bf16 round-to-nearest-even helpers
__device__ __forceinline__ unsigned short rne(float f) {
    unsigned u = __float_as_uint(f);
    return (unsigned short)((u + 0x7fffu + ((u >> 16) & 1u)) >> 16);
}
__device__ __forceinline__ float b2f(unsigned short b) {
    return __uint_as_float(((unsigned)b) << 16);
}

// 16-slot hi/lo-split encoding (validated rounds 4-10, absmax 0)
__device__ __forceinline__ void encDf(float x, float y, float z, s16x8& lo, s16x8& hi) {
    const unsigned short hx = rne(x), hy = rne(y), hz = rne(z);
    const float fx = b2f(hx), fy = b2f(hy), fz = b2f(hz);
    const unsigned short lx = rne(x - fx), ly = rne(y - fy), lz = rne(z - fz);
    const float n = fmaf(x, x, fmaf(y, y, z * z));
    const unsigned short nh = rne(n), nl = rne(n - b2f(nh));
    const unsigned short m2hx = rne(-2.f * fx), m2hy = rne(-2.f * fy), m2hz = rne(-2.f * fz);
    const unsigned short m2lx = rne(-2.f * b2f(lx)), m2ly = rne(-2.f * b2f(ly)), m2lz = rne(-2.f * b2f(lz));
    lo[0]=(short)m2hx; lo[1]=(short)m2hy; lo[2]=(short)m2hz; lo[3]=(short)m2hx;
    lo[4]=(short)m2hy; lo[5]=(short)m2hz; lo[6]=(short)m2lx; lo[7]=(short)m2ly;
    hi[0]=(short)m2lz; hi[1]=(short)0x3f80; hi[2]=(short)0x3f80; hi[3]=(short)nh;
    hi[4]=(short)nl;   hi[5]=(short)m2lx;  hi[6]=(short)m2ly;   hi[7]=(short)m2lz;
}

__device__ __forceinline__ void encQf(float x, float y, float z, s16x8& lo, s16x8& hi) {
    const unsigned short hx = rne(x), hy = rne(y), hz = rne(z);
    const float fx = b2f(hx), fy = b2f(hy), fz = b2f(hz);
    const unsigned short lx = rne(x - fx), ly = rne(y - fy), lz = rne(z - fz);
    const float n = fmaf(x, x, fmaf(y, y, z * z));
    const unsigned short nh = rne(n), nl = rne(n - b2f(nh));
    lo[0]=(short)hx; lo[1]=(short)hy; lo[2]=(short)hz; lo[3]=(short)lx;
    lo[4]=(short)ly; lo[5]=(short)lz; lo[6]=(short)hx; lo[7]=(short)hy;
    hi[0]=(short)hz; hi[1]=(short)nh; hi[2]=(short)nl; hi[3]=(short)0x3f80;
    hi[4]=(short)0x3f80; hi[5]=(short)lx; hi[6]=(short)ly; hi[7]=(short)lz;
}

// ---------------------------------------------------------------------------
// preproc: encode every point once to global. D layout: contiguous 16 KiB per
// 512-point chunk (linear-stageable); Q layout: per-tile lane fragments.
// Also zeroes acc/ticket for the downstream reduce (stream-ordered).
// ---------------------------------------------------------------------------
__global__ void __launch_bounds__(256) preproc(
    const float* __restrict__ pred, const float* __restrict__ tgt,
    char* __restrict__ encQp, char* __restrict__ encQt,
    char* __restrict__ encDp, char* __restrict__ encDt,
    unsigned long long* __restrict__ acc, unsigned* __restrict__ ticket)
{
    const int pid = blockIdx.x * 256 + threadIdx.x;     // [0, 65536)
    if (pid == 0) { *acc = 0ull; *ticket = 0u; }
    const int which = pid >> 15, p = pid & 32767;
    const float* __restrict__ src = which ? tgt : pred;
    char* __restrict__ eQ = which ? encQt : encQp;
    char* __restrict__ eD = which ? encDt : encDp;

    const float x = src[p * 3], y = src[p * 3 + 1], z = src[p * 3 + 2];
    const int b = p >> 13, i = p & 8191;

    s16x8 qlo, qhi, dlo, dhi;
    encQf(x, y, z, qlo, qhi);
    encDf(x, y, z, dlo, dhi);

    {   // db-role
        const int split = i >> 9, idx = i & 511, tile = idx >> 5, pt = idx & 31;
        char* base = eD + (((size_t)(b * 16 + split)) << 14) + (tile << 10) + (pt << 4);
        *(s16x8*)base = dlo;
        *(s16x8*)(base + 512) = dhi;
    }
    {   // query-role
        const int tile = i >> 5, pt = i & 31;
        char* base = eQ + (((size_t)(b * 256 + tile)) << 10) + (pt << 4);
        *(s16x8*)base = qlo;
        *(s16x8*)(base + 512) = qhi;
    }
}

// ---------------------------------------------------------------------------
// minpass: bid fields qg(32) | split(16) | b(4) | pass(2). UNPINNED schedule:
// fully-unrolled loop, no sched_barriers, no volatile -- the compiler
// software-pipelines 32 MFMAs + 32 guarded folds + 16 ds_reads globally
// (R10 diagnostic: MFMA+LDS alone = 10.25us/rep @ 79% MfmaUtil; the pinned
// lockstep of folds was the 2.5x interaction cost).
// ---------------------------------------------------------------------------
__global__ void __launch_bounds__(256) minpass(
    const char* __restrict__ encQp, const char* __restrict__ encQt,
    const char* __restrict__ encDp, const char* __restrict__ encDt,
    float* __restrict__ part)
{
    __shared__ s16x8 sdb[16 * 64];   // [tile][half*32+pt], 16 KiB

    const int bid = blockIdx.x;
    const int qg = bid & 31, split = (bid >> 5) & 15, b = (bid >> 9) & 3, pass = bid >> 11;
    const char* __restrict__ eQ = pass ? encQt : encQp;
    const char* __restrict__ eD = pass ? encDp : encDt;

    const int tid = threadIdx.x, lane = tid & 63, wid = tid >> 6;

    // stage pre-encoded db chunk: pure linear 16 KiB copy
    {
        const int4* __restrict__ gs = (const int4*)(eD + (((size_t)(b * 16 + split)) << 14));
        int4* ld = (int4*)sdb;
        int4 r0 = gs[tid], r1 = gs[tid + 256], r2 = gs[tid + 512], r3 = gs[tid + 768];
        ld[tid] = r0; ld[tid + 256] = r1; ld[tid + 512] = r2; ld[tid + 768] = r3;
    }

    // query fragments: 2 tiles per wave, one 16B load each
    const int tq = qg * 8 + wid * 2;
    const s16x8* __restrict__ qa = (const s16x8*)(eQ + (((size_t)(b * 256 + tq)) << 10));
    const s16x8 aq0 = qa[lane];
    const s16x8 aq1 = qa[64 + lane];

    float mn0 = 3.4e38f, mn1 = 3.4e38f;

    __syncthreads();

#pragma unroll
    for (int t = 0; t < 16; t += 2) {
        const s16x8 d0 = sdb[t * 64 + lane];
        const s16x8 d1 = sdb[t * 64 + 64 + lane];
        f32x16 a00 = mfma0(d0, aq0);
        f32x16 a01 = mfma0(d0, aq1);
        f32x16 a10 = mfma0(d1, aq0);
        f32x16 a11 = mfma0(d1, aq1);
        GUARD(a00); mn0 = fold16(mn0, a00);
        GUARD(a01); mn1 = fold16(mn1, a01);
        GUARD(a10); mn0 = fold16(mn0, a10);
        GUARD(a11); mn1 = fold16(mn1, a11);
    }

    mn0 = fmaxf(fminf(mn0, __shfl_xor(mn0, 32)), 0.0f);
    mn1 = fmaxf(fminf(mn1, __shfl_xor(mn1, 32)), 0.0f);

    if (lane < 32) {
        const size_t qi = ((size_t)pass << 15) + ((size_t)b << 13) + (size_t)tq * 32 + lane;
        part[(size_t)split * 65536 + qi]      = mn0;
        part[(size_t)split * 65536 + qi + 32] = mn1;
    }
}

// ---------------------------------------------------------------------------
// reduce + writeout: fold 16 split-partials per query (coalesced), sqrt, sum
// via fixed-point u64 (order-independent -> deterministic); last-ticket block
// writes the scalar.
// ---------------------------------------------------------------------------
#define FIXSCALE 1099511627776.0   // 2^40
#define RBLOCKS 128

__global__ void __launch_bounds__(256) reduce_writeout(
    const float* __restrict__ part, unsigned long long* __restrict__ acc,
    unsigned* __restrict__ ticket, float* __restrict__ out)
{
    const int q0 = blockIdx.x * 512 + threadIdx.x;
    float s = 0.0f;
#pragma unroll
    for (int k = 0; k < 2; ++k) {
        const int qi = q0 + k * 256;
        float v = part[qi];
#pragma unroll
        for (int sp = 1; sp < 16; ++sp) v = fminf(v, part[(size_t)sp * 65536 + qi]);
        s += sqrtf(v);
    }
    for (int off = 32; off; off >>= 1) s += __shfl_down(s, off, 64);
    __shared__ float ws[4];
    if ((threadIdx.x & 63) == 0) ws[threadIdx.x >> 6] = s;
    __syncthreads();
    if (threadIdx.x == 0) {
        const double t = (double)(ws[0] + ws[1] + ws[2] + ws[3]) * (1.0 / 32768.0);
        atomicAdd(acc, (unsigned long long)(t * FIXSCALE));
        __threadfence();
        const unsigned tk = atomicAdd(ticket, 1u);
        if (tk == RBLOCKS - 1) {
            const unsigned long long v = atomicAdd(acc, 0ull);
            out[0] = (float)((double)v * (1.0 / FIXSCALE));
        }
    }
}

// ---------------------------------------------------------------------------
extern "C" void kernel_launch(void* const* d_in, const int* in_sizes, int n_in,
                              void* d_out, int out_size, void* d_ws, size_t ws_size,
                              hipStream_t stream) {
    const float* pred   = (const float*)d_in[0];   // [4,8192,3]
    const float* target = (const float*)d_in[1];   // [4,8192,3]
    float* out = (float*)d_out;

    char* encQp = (char*)d_ws;                       // 1 MiB each
    char* encQt = encQp + (1u << 20);
    char* encDp = encQp + (2u << 20);
    char* encDt = encQp + (3u << 20);
    float* part = (float*)(encQp + (4u << 20));      // [16][65536] = 4 MiB
    unsigned long long* acc = (unsigned long long*)(encQp + (8u << 20));
    unsigned* ticket = (unsigned*)(acc + 1);

    preproc<<<256, 256, 0, stream>>>(pred, target, encQp, encQt, encDp, encDt, acc, ticket);

    minpass<<<4096, 256, 0, stream>>>(encQp, encQt, encDp, encDt, part);

    reduce_writeout<<<RBLOCKS, 256, 0, stream>>>(part, acc, ticket, out);
}

// Round 12
// 32.971 us; speedup vs baseline: 4.5077x; 1.0366x over previous
//
#include <hip/hip_runtime.h>

typedef short s16x8 __attribute__((ext_vector_type(8)));
typedef float f32x16 __attribute__((ext_vector_type(16)));

// MFMA in VGPRs via asm ("v" forbids AGPR; "=&v" keeps dst disjoint).
__device__ __forceinline__ f32x16 mfma0(s16x8 a, s16x8 b) {
    f32x16 d;
    asm("v_mfma_f32_32x32x16_bf16 %0, %1, %2, 0" : "=&v"(d) : "v"(a), "v"(b));
    return d;
}

#define VMIN3(d, a, b, c) \
    asm("v_min3_f32 %0, %1, %2, %3" : "=v"(d) : "v"(a), "v"(b), "v"(c))

#define FOLD16(mn, A) { \
        float u0, u1, u2, u3, u4, v0, v1; \
        VMIN3(u0, A[0],  A[1],  A[2]); \
        VMIN3(u1, A[3],  A[4],  A[5]); \
        VMIN3(u2, A[6],  A[7],  A[8]); \
        VMIN3(u3, A[9],  A[10], A[11]); \
        VMIN3(u4, A[12], A[13], A[14]); \
        VMIN3(v0, u0, u1, u2); \
        VMIN3(v1, u3, u4, A[15]); \
        VMIN3(mn, v0, v1, mn); \
    }

// bf16 round-to-nearest-even helpers
__device__ __forceinline__ unsigned short rne(float f) {
    unsigned u = __float_as_uint(f);
    return (unsigned short)((u + 0x7fffu + ((u >> 16) & 1u)) >> 16);
}
__device__ __forceinline__ float b2f(unsigned short b) {
    return __uint_as_float(((unsigned)b) << 16);
}

// 16-slot hi/lo-split encoding (validated rounds 4-11, absmax 0)
__device__ __forceinline__ void encDf(float x, float y, float z, s16x8& lo, s16x8& hi) {
    const unsigned short hx = rne(x), hy = rne(y), hz = rne(z);
    const float fx = b2f(hx), fy = b2f(hy), fz = b2f(hz);
    const unsigned short lx = rne(x - fx), ly = rne(y - fy), lz = rne(z - fz);
    const float n = fmaf(x, x, fmaf(y, y, z * z));
    const unsigned short nh = rne(n), nl = rne(n - b2f(nh));
    const unsigned short m2hx = rne(-2.f * fx), m2hy = rne(-2.f * fy), m2hz = rne(-2.f * fz);
    const unsigned short m2lx = rne(-2.f * b2f(lx)), m2ly = rne(-2.f * b2f(ly)), m2lz = rne(-2.f * b2f(lz));
    lo[0]=(short)m2hx; lo[1]=(short)m2hy; lo[2]=(short)m2hz; lo[3]=(short)m2hx;
    lo[4]=(short)m2hy; lo[5]=(short)m2hz; lo[6]=(short)m2lx; lo[7]=(short)m2ly;
    hi[0]=(short)m2lz; hi[1]=(short)0x3f80; hi[2]=(short)0x3f80; hi[3]=(short)nh;
    hi[4]=(short)nl;   hi[5]=(short)m2lx;  hi[6]=(short)m2ly;   hi[7]=(short)m2lz;
}

__device__ __forceinline__ void encQf(float x, float y, float z, s16x8& lo, s16x8& hi) {
    const unsigned short hx = rne(x), hy = rne(y), hz = rne(z);
    const float fx = b2f(hx), fy = b2f(hy), fz = b2f(hz);
    const unsigned short lx = rne(x - fx), ly = rne(y - fy), lz = rne(z - fz);
    const float n = fmaf(x, x, fmaf(y, y, z * z));
    const unsigned short nh = rne(n), nl = rne(n - b2f(nh));
    lo[0]=(short)hx; lo[1]=(short)hy; lo[2]=(short)hz; lo[3]=(short)lx;
    lo[4]=(short)ly; lo[5]=(short)lz; lo[6]=(short)hx; lo[7]=(short)hy;
    hi[0]=(short)hz; hi[1]=(short)nh; hi[2]=(short)nl; hi[3]=(short)0x3f80;
    hi[4]=(short)0x3f80; hi[5]=(short)lx; hi[6]=(short)ly; hi[7]=(short)lz;
}

// ---------------------------------------------------------------------------
// preproc: encode every point once to global (proven R9). D: contiguous
// 16 KiB per 512-point chunk. Q: per-tile lane fragments. Zeroes acc/ticket.
// ---------------------------------------------------------------------------
__global__ void __launch_bounds__(256) preproc(
    const float* __restrict__ pred, const float* __restrict__ tgt,
    char* __restrict__ encQp, char* __restrict__ encQt,
    char* __restrict__ encDp, char* __restrict__ encDt,
    unsigned long long* __restrict__ acc, unsigned* __restrict__ ticket)
{
    const int pid = blockIdx.x * 256 + threadIdx.x;     // [0, 65536)
    if (pid == 0) { *acc = 0ull; *ticket = 0u; }
    const int which = pid >> 15, p = pid & 32767;
    const float* __restrict__ src = which ? tgt : pred;
    char* __restrict__ eQ = which ? encQt : encQp;
    char* __restrict__ eD = which ? encDt : encDp;

    const float x = src[p * 3], y = src[p * 3 + 1], z = src[p * 3 + 2];
    const int b = p >> 13, i = p & 8191;

    s16x8 qlo, qhi, dlo, dhi;
    encQf(x, y, z, qlo, qhi);
    encDf(x, y, z, dlo, dhi);

    {   // db-role
        const int chunk = i >> 9, idx = i & 511, tile = idx >> 5, pt = idx & 31;
        char* base = eD + (((size_t)(b * 16 + chunk)) << 14) + (tile << 10) + (pt << 4);
        *(s16x8*)base = dlo;
        *(s16x8*)(base + 512) = dhi;
    }
    {   // query-role
        const int tile = i >> 5, pt = i & 31;
        char* base = eQ + (((size_t)(b * 256 + tile)) << 10) + (pt << 4);
        *(s16x8*)base = qlo;
        *(s16x8*)(base + 512) = qhi;
    }
}

// ---------------------------------------------------------------------------
// minpass: PERSISTENT blocks. Grid = 256 = pass(2) x b(4) x half(2) x qg(16),
// one block per CU. Each wave owns 4 query tiles (aq0..3, halves LDS traffic);
// block sweeps 8 db chunks (4096 points = its half) with double-buffered LDS:
// issue next chunk's global loads to regs BEFORE compute (T14), ds_write after.
// Inner loop: R8-proven phase pipeline, ds prefetch 2 tiles ahead, >=32cyc
// MFMA->fold separation. One prologue per CU instead of sixteen (R10 fit:
// fixed cost F~24us scaled with 4096 short-lived blocks, marginal compute 3us).
// ---------------------------------------------------------------------------
__global__ void __launch_bounds__(256) minpass(
    const char* __restrict__ encQp, const char* __restrict__ encQt,
    const char* __restrict__ encDp, const char* __restrict__ encDt,
    float* __restrict__ part)
{
    __shared__ s16x8 sdb[2][16 * 64];   // double buffer, 2 x 16 KiB

    const int bid = blockIdx.x;
    const int qg = bid & 15, half = (bid >> 4) & 1, b = (bid >> 5) & 3, pass = bid >> 7;
    const char* __restrict__ eQ = pass ? encQt : encQp;
    const char* __restrict__ eD = pass ? encDp : encDt;

    const int tid = threadIdx.x, lane = tid & 63, wid = tid >> 6;
    const int c0 = half * 8;

    // query fragments: 4 tiles per wave
    const int tq = qg * 16 + wid * 4;
    const s16x8* __restrict__ qa = (const s16x8*)(eQ + (((size_t)(b * 256 + tq)) << 10));
    const s16x8 aq0 = qa[lane];
    const s16x8 aq1 = qa[64 + lane];
    const s16x8 aq2 = qa[128 + lane];
    const s16x8 aq3 = qa[192 + lane];

    // prologue: stage chunk c0 into buffer 0
    {
        const int4* __restrict__ gs = (const int4*)(eD + (((size_t)(b * 16 + c0)) << 14));
        int4 r0 = gs[tid], r1 = gs[tid + 256], r2 = gs[tid + 512], r3 = gs[tid + 768];
        int4* ld = (int4*)&sdb[0][0];
        ld[tid] = r0; ld[tid + 256] = r1; ld[tid + 512] = r2; ld[tid + 768] = r3;
    }

    float mn0 = 3.4e38f, mn1 = 3.4e38f, mn2 = 3.4e38f, mn3 = 3.4e38f;

    __syncthreads();

    int cur = 0;
    for (int c = 0; c < 8; ++c) {
        // issue next chunk's loads early: latency hides under compute
        int4 r0, r1, r2, r3;
        if (c + 1 < 8) {
            const int4* __restrict__ gs =
                (const int4*)(eD + (((size_t)(b * 16 + c0 + c + 1)) << 14));
            r0 = gs[tid]; r1 = gs[tid + 256]; r2 = gs[tid + 512]; r3 = gs[tid + 768];
        }

        const s16x8* __restrict__ S = &sdb[cur][0];
        s16x8 d0 = S[lane];
        s16x8 d1 = S[64 + lane];
        f32x16 P0 = mfma0(d0, aq0);
        f32x16 P1 = mfma0(d0, aq1);
        asm volatile("s_nop 7\n\ts_nop 7");

#pragma unroll
        for (int t = 0; t < 16; ++t) {
            __builtin_amdgcn_sched_barrier(0);
            // phase 1: issue 2nd half of tile t; prefetch tile t+2; fold 1st half
            f32x16 Q0 = mfma0(d0, aq2);
            f32x16 Q1 = mfma0(d0, aq3);
            s16x8 dn = d0;
            if (t + 2 < 16) dn = S[(t + 2) * 64 + lane];
            FOLD16(mn0, P0);
            FOLD16(mn1, P1);
            __builtin_amdgcn_sched_barrier(0);
            // phase 2: issue 1st half of tile t+1; fold 2nd half of tile t
            if (t + 1 < 16) {
                P0 = mfma0(d1, aq0);
                P1 = mfma0(d1, aq1);
            }
            FOLD16(mn2, Q0);
            FOLD16(mn3, Q1);
            d0 = d1; d1 = dn;
        }
        __builtin_amdgcn_sched_barrier(0);

        // write staged regs into the other buffer, then swap
        if (c + 1 < 8) {
            int4* ld = (int4*)&sdb[cur ^ 1][0];
            ld[tid] = r0; ld[tid + 256] = r1; ld[tid + 512] = r2; ld[tid + 768] = r3;
        }
        __syncthreads();
        cur ^= 1;
    }

    mn0 = fmaxf(fminf(mn0, __shfl_xor(mn0, 32)), 0.0f);
    mn1 = fmaxf(fminf(mn1, __shfl_xor(mn1, 32)), 0.0f);
    mn2 = fmaxf(fminf(mn2, __shfl_xor(mn2, 32)), 0.0f);
    mn3 = fmaxf(fminf(mn3, __shfl_xor(mn3, 32)), 0.0f);

    if (lane < 32) {
        const size_t qi = ((size_t)pass << 15) + ((size_t)b << 13) + (size_t)tq * 32 + lane;
        float* __restrict__ po = part + (size_t)half * 65536;
        po[qi]      = mn0;
        po[qi + 32] = mn1;
        po[qi + 64] = mn2;
        po[qi + 96] = mn3;
    }
}

// ---------------------------------------------------------------------------
// reduce + writeout: min over the 2 half-splits, sqrt, sum via fixed-point u64
// (order-independent -> deterministic); last-ticket block writes the scalar.
// ---------------------------------------------------------------------------
#define FIXSCALE 1099511627776.0   // 2^40
#define RBLOCKS 64

__global__ void __launch_bounds__(256) reduce_writeout(
    const float* __restrict__ part, unsigned long long* __restrict__ acc,
    unsigned* __restrict__ ticket, float* __restrict__ out)
{
    const int q0 = blockIdx.x * 1024 + threadIdx.x;
    float s = 0.0f;
#pragma unroll
    for (int k = 0; k < 4; ++k) {
        const int qi = q0 + k * 256;
        s += sqrtf(fminf(part[qi], part[65536 + qi]));
    }
    for (int off = 32; off; off >>= 1) s += __shfl_down(s, off, 64);
    __shared__ float ws[4];
    if ((threadIdx.x & 63) == 0) ws[threadIdx.x >> 6] = s;
    __syncthreads();
    if (threadIdx.x == 0) {
        const double t = (double)(ws[0] + ws[1] + ws[2] + ws[3]) * (1.0 / 32768.0);
        atomicAdd(acc, (unsigned long long)(t * FIXSCALE));
        __threadfence();
        const unsigned tk = atomicAdd(ticket, 1u);
        if (tk == RBLOCKS - 1) {
            const unsigned long long v = atomicAdd(acc, 0ull);
            out[0] = (float)((double)v * (1.0 / FIXSCALE));
        }
    }
}

// ---------------------------------------------------------------------------
extern "C" void kernel_launch(void* const* d_in, const int* in_sizes, int n_in,
                              void* d_out, int out_size, void* d_ws, size_t ws_size,
                              hipStream_t stream) {
    const float* pred   = (const float*)d_in[0];   // [4,8192,3]
    const float* target = (const float*)d_in[1];   // [4,8192,3]
    float* out = (float*)d_out;

    char* encQp = (char*)d_ws;                       // 1 MiB each
    char* encQt = encQp + (1u << 20);
    char* encDp = encQp + (2u << 20);
    char* encDt = encQp + (3u << 20);
    float* part = (float*)(encQp + (4u << 20));      // [2][65536] = 512 KiB
    unsigned long long* acc = (unsigned long long*)(encQp + (5u << 20));
    unsigned* ticket = (unsigned*)(acc + 1);

    preproc<<<256, 256, 0, stream>>>(pred, target, encQp, encQt, encDp, encDt, acc, ticket);

    minpass<<<256, 256, 0, stream>>>(encQp, encQt, encDp, encDt, part);

    reduce_writeout<<<RBLOCKS, 256, 0, stream>>>(part, acc, ticket, out);
}